// Round 4
// baseline (30965.851 us; speedup 1.0000x reference)
//
#include <hip/hip_runtime.h>
#include <math.h>

#define D_IN    1024
#define D_CELL  2048
#define T_STEPS 2048
#define D_Z     3072            // D_IN + D_CELL
#define R_TOTAL (4 * D_CELL)    // 8192 gate rows
#define NBLK    512             // 4 cells/block, 2 blocks/CU
#define NTHR    512             // 8 waves

typedef unsigned long long u64;

// ---------------------------------------------------------------------------
// init: zero the h-exchange slots (harness does NOT re-poison ws between
// timed replays; stale tags from a previous replay would satisfy polls).
// slots = u64[2][D_CELL], slot = (tag<<32)|f32bits(h)
// ---------------------------------------------------------------------------
__global__ void lstm_init_kernel(u64* __restrict__ slots) {
    int i = blockIdx.x * 256 + threadIdx.x;
    if (i < 2 * D_CELL) slots[i] = 0ull;
}

// ---------------------------------------------------------------------------
// Gx[r][t] = b[r] + sum_k W_g[d][k] * x[k][t]   (k < 1024, input part)
// 1D grid of 2048 blocks, XCD-aware decode: each XCD works on ONE t-half
// (same 4 MiB x tile -> fits its private 4 MiB L2). 256 threads, each
// handles 4 t-columns x 8 rows. W row loads are wave-uniform -> s_load.
// ---------------------------------------------------------------------------
__global__ __launch_bounds__(256) void lstm_gx_kernel(
    const float* __restrict__ Wf, const float* __restrict__ bf,
    const float* __restrict__ Wi, const float* __restrict__ bi,
    const float* __restrict__ Wc, const float* __restrict__ bc,
    const float* __restrict__ Wo, const float* __restrict__ bo,
    const float* __restrict__ x,  float* __restrict__ Gx)
{
    const int bid = blockIdx.x;          // 0..2047
    const int xcd = bid & 7;             // HW round-robin: bid%8 = XCD
    const int loc = bid >> 3;            // 0..255
    const int tx  = xcd >> 2;            // t-half 0/1 (4 XCDs per half)
    const int yb  = (xcd & 3) * 256 + loc;   // row-block 0..1023
    const int tid = threadIdx.x;
    const int t0  = tx * 1024 + tid * 4;
    const int r0  = yb * 8;
    const int g   = r0 >> 11;
    const int d0  = r0 & 2047;
    const float* W = (g == 0) ? Wf : (g == 1) ? Wi : (g == 2) ? Wc : Wo;
    const float* b = (g == 0) ? bf : (g == 1) ? bi : (g == 2) ? bc : bo;

    const float* wr0 = W + (size_t)(d0 + 0) * D_Z;
    const float* wr1 = W + (size_t)(d0 + 1) * D_Z;
    const float* wr2 = W + (size_t)(d0 + 2) * D_Z;
    const float* wr3 = W + (size_t)(d0 + 3) * D_Z;
    const float* wr4 = W + (size_t)(d0 + 4) * D_Z;
    const float* wr5 = W + (size_t)(d0 + 5) * D_Z;
    const float* wr6 = W + (size_t)(d0 + 6) * D_Z;
    const float* wr7 = W + (size_t)(d0 + 7) * D_Z;

    float4 acc[8];
#pragma unroll
    for (int jr = 0; jr < 8; ++jr) acc[jr] = make_float4(0.f, 0.f, 0.f, 0.f);

    for (int k = 0; k < D_IN; k += 4) {
        float4 xa = *(const float4*)(x + (size_t)(k + 0) * T_STEPS + t0);
        float4 xb = *(const float4*)(x + (size_t)(k + 1) * T_STEPS + t0);
        float4 xc = *(const float4*)(x + (size_t)(k + 2) * T_STEPS + t0);
        float4 xd = *(const float4*)(x + (size_t)(k + 3) * T_STEPS + t0);
        const float* wrs[8] = {wr0, wr1, wr2, wr3, wr4, wr5, wr6, wr7};
#pragma unroll
        for (int jr = 0; jr < 8; ++jr) {
            float4 w = *(const float4*)(wrs[jr] + k);   // wave-uniform
            acc[jr].x += w.x * xa.x + w.y * xb.x + w.z * xc.x + w.w * xd.x;
            acc[jr].y += w.x * xa.y + w.y * xb.y + w.z * xc.y + w.w * xd.y;
            acc[jr].z += w.x * xa.z + w.y * xb.z + w.z * xc.z + w.w * xd.z;
            acc[jr].w += w.x * xa.w + w.y * xb.w + w.z * xc.w + w.w * xd.w;
        }
    }

#pragma unroll
    for (int jr = 0; jr < 8; ++jr) {
        float bb = b[d0 + jr];
        float4 o = acc[jr];
        o.x += bb; o.y += bb; o.z += bb; o.w += bb;
        *(float4*)(Gx + (size_t)(r0 + jr) * T_STEPS + t0) = o;
    }
}

// ---------------------------------------------------------------------------
// Persistent recurrence kernel. 512 blocks x 512 threads (8 waves, 4 cells,
// 2 blocks/CU — residency capacity is 4 blocks/CU so co-residency is
// guaranteed). Wave pair (2c, 2c+1) owns cell c: wave 2c has gate rows
// {4c,4c+1} (f,i), wave 2c+1 has {4c+2,4c+3} (cand,o). Per-wave weight code
// is identical to the proven round-0/3 shape (64 fp32/lane, compiler keeps
// them on-chip in AGPRs — do NOT add register-class asm, see round 2).
// Per step: batched 4-slot poll -> hs[par] (double-buffered LDS) -> sync A
// (the ONLY barrier) -> dot -> butterfly. Odd wave posts its 2 row-sums to
// tagged LDS u64 slots and falls straight into the t+1 poll; even wave spins
// on those 2 slots, computes the activation redundantly on all lanes, and
// publishes immediately. Cell c's publish waits only on its own pair, not on
// all 8 waves — sync B is gone and the tail overlaps remote fabric latency.
// Safety of no-sync-B: hs is double-buffered; gslot(t) is consumed before
// any wave can pass sync A(t+1), because sync A(t+1) is gated on this very
// pair's publish of tag t+1.
// ---------------------------------------------------------------------------
__global__ __launch_bounds__(NTHR, 4) void lstm_rec_kernel(
    const float* __restrict__ Wf, const float* __restrict__ Wi,
    const float* __restrict__ Wc, const float* __restrict__ Wo,
    const float* __restrict__ Gx, u64* __restrict__ slots,
    float* __restrict__ out)
{
    __shared__ float hs[2][D_CELL];  // h_{t-1}, double-buffered
    __shared__ u64   gslot[8];       // tagged (cand,o) sums: cell cp -> 2cp,2cp+1

    const int tid  = threadIdx.x;
    const int w    = tid >> 6;       // wave 0..7
    const int lane = tid & 63;
    const int r0   = 2 * w;          // rows r0, r0+1  (row = cell*4 + gate)
    const int cp   = w >> 1;         // owned cell 0..3

    // ---- load my two weight rows (fp32, stay on-chip in VGPRs/AGPRs) ----
    const int g0 = r0 & 3,        g1 = (r0 + 1) & 3;
    const int cl = r0 >> 2;                       // same cell for both rows
    const int d  = blockIdx.x * 4 + cl;           // global cell
    const float* Wb0 = ((g0 == 0) ? Wf : (g0 == 1) ? Wi : (g0 == 2) ? Wc : Wo)
                       + (size_t)d * D_Z + D_IN;
    const float* Wb1 = ((g1 == 0) ? Wf : (g1 == 1) ? Wi : (g1 == 2) ? Wc : Wo)
                       + (size_t)d * D_Z + D_IN;
    float4 wA[8], wB[8];
#pragma unroll
    for (int j = 0; j < 8; ++j) {
        wA[j] = *(const float4*)(Wb0 + j * 256 + lane * 4);
        wB[j] = *(const float4*)(Wb1 + j * 256 + lane * 4);
    }

    // Gx row base for lanes 0,1 (lane L handles row r0+L)
    const int myrow = r0 + (lane & 1);
    const size_t gxbase = (size_t)((myrow & 3) * D_CELL
                                   + blockIdx.x * 4 + (myrow >> 2)) * T_STEPS;

    if (tid < 8) gslot[tid] = 0ull;  // wipe LDS garbage (ordered by sync A(0))

    float cst = 0.f;                 // cell state (even waves, lane-redundant)
    const float L2E  = 1.442695041f;     // log2(e)
    const float L2E2 = 2.885390082f;     // 2*log2(e)

    for (int t = 0; t < T_STEPS; ++t) {
        // prefetch Gx early (independent of poll)
        float gx_pref = 0.f;
        if (lane < 2) gx_pref = Gx[gxbase + t];

        const int par = t & 1;
        if (t == 0) {
            *(float4*)&hs[0][4 * tid] = make_float4(0.f, 0.f, 0.f, 0.f);
        } else {
            // batched poll of my 4 slots: one combined tag check
            const u64* bp = slots + (size_t)par * D_CELL + 4 * tid;
            const u64 tg = (u64)(unsigned)t << 32;
            u64 a, b, e, f;
            for (;;) {
                a = __hip_atomic_load(bp + 0, __ATOMIC_RELAXED,
                                      __HIP_MEMORY_SCOPE_AGENT);
                b = __hip_atomic_load(bp + 1, __ATOMIC_RELAXED,
                                      __HIP_MEMORY_SCOPE_AGENT);
                e = __hip_atomic_load(bp + 2, __ATOMIC_RELAXED,
                                      __HIP_MEMORY_SCOPE_AGENT);
                f = __hip_atomic_load(bp + 3, __ATOMIC_RELAXED,
                                      __HIP_MEMORY_SCOPE_AGENT);
                if (((((a ^ tg) | (b ^ tg)) | ((e ^ tg) | (f ^ tg))) >> 32) == 0)
                    break;
                __builtin_amdgcn_s_sleep(1);
            }
            *(float4*)&hs[par][4 * tid] =
                make_float4(__uint_as_float((unsigned)a),
                            __uint_as_float((unsigned)b),
                            __uint_as_float((unsigned)e),
                            __uint_as_float((unsigned)f));
        }
        __syncthreads();                          // sync A: hs[par] ready

        // ---- two gate-row dot slices from on-chip weights ----
        float acc0 = 0.f, acc1 = 0.f;
#pragma unroll
        for (int j = 0; j < 8; ++j) {
            float4 h = *(const float4*)&hs[par][j * 256 + lane * 4];
            acc0 += wA[j].x * h.x + wA[j].y * h.y + wA[j].z * h.z + wA[j].w * h.w;
            acc1 += wB[j].x * h.x + wB[j].y * h.y + wB[j].z * h.z + wB[j].w * h.w;
        }
        // paired butterfly: lane ends with FULL sum of row r0+(lane&1)
        float vK = (lane & 1) ? acc1 : acc0;
        float vO = (lane & 1) ? acc0 : acc1;
        float v  = vK + __shfl_xor(vO, 1);
        v += __shfl_xor(v, 2);
        v += __shfl_xor(v, 4);
        v += __shfl_xor(v, 8);
        v += __shfl_xor(v, 16);
        v += __shfl_xor(v, 32);

        if (w & 1) {
            // ---- odd wave: post (cand, o) sums, fall into next poll ----
            if (lane < 2) {
                u64 pk = ((u64)(unsigned)(t + 1) << 32)
                       | (u64)__float_as_uint(v + gx_pref);
                __hip_atomic_store(&gslot[2 * cp + lane], pk,
                                   __ATOMIC_RELAXED, __HIP_MEMORY_SCOPE_WORKGROUP);
            }
        } else {
            // ---- even wave: gf,gi in-register; gc,go from pair slots ----
            float vs  = __shfl_xor(v, 1);
            float gxA = __shfl(gx_pref, 0);
            float gxB = __shfl(gx_pref, 1);
            float gf = ((lane & 1) ? vs : v) + gxA;
            float gi = ((lane & 1) ? v : vs) + gxB;

            const u64 tgl = (u64)(unsigned)(t + 1) << 32;
            u64 s2, s3;
            for (;;) {
                s2 = __hip_atomic_load(&gslot[2 * cp + 0], __ATOMIC_RELAXED,
                                       __HIP_MEMORY_SCOPE_WORKGROUP);
                s3 = __hip_atomic_load(&gslot[2 * cp + 1], __ATOMIC_RELAXED,
                                       __HIP_MEMORY_SCOPE_WORKGROUP);
                if ((((s2 ^ tgl) | (s3 ^ tgl)) >> 32) == 0) break;
            }
            float gc = __uint_as_float((unsigned)s2);
            float go = __uint_as_float((unsigned)s3);

            // fast activations (validated: identical absmax since round 1)
            float f    = __builtin_amdgcn_rcpf(
                             1.f + __builtin_amdgcn_exp2f(-L2E * gf));
            float ig   = __builtin_amdgcn_rcpf(
                             1.f + __builtin_amdgcn_exp2f(-L2E * gi));
            float o    = __builtin_amdgcn_rcpf(
                             1.f + __builtin_amdgcn_exp2f(-L2E * go));
            float cand = 1.f - 2.f * __builtin_amdgcn_rcpf(
                             __builtin_amdgcn_exp2f(L2E2 * gc) + 1.f);
            cst = f * cst + ig * cand;
            float tc   = 1.f - 2.f * __builtin_amdgcn_rcpf(
                             __builtin_amdgcn_exp2f(L2E2 * cst) + 1.f);
            float hn = o * tc;

            if (lane == 0) {
                const int dg = blockIdx.x * 4 + cp;
                if (t + 1 < T_STEPS) {            // publish FIRST
                    u64 pk = ((u64)(unsigned)(t + 1) << 32)
                           | (u64)__float_as_uint(hn);
                    __hip_atomic_store(
                        slots + (size_t)((t + 1) & 1) * D_CELL + dg,
                        pk, __ATOMIC_RELAXED, __HIP_MEMORY_SCOPE_AGENT);
                }
                out[(size_t)dg * T_STEPS + t] = hn;
            }
        }
    }
}

// ---------------------------------------------------------------------------
extern "C" void kernel_launch(void* const* d_in, const int* in_sizes, int n_in,
                              void* d_out, int out_size, void* d_ws, size_t ws_size,
                              hipStream_t stream) {
    const float* x  = (const float*)d_in[0];
    const float* Wf = (const float*)d_in[1];
    const float* bf = (const float*)d_in[2];
    const float* Wi = (const float*)d_in[3];
    const float* bi = (const float*)d_in[4];
    const float* Wc = (const float*)d_in[5];
    const float* bc = (const float*)d_in[6];
    const float* Wo = (const float*)d_in[7];
    const float* bo = (const float*)d_in[8];
    float* out = (float*)d_out;

    // ws layout: Gx fp32 [8192][2048] | slots u64 [2][2048]
    const size_t gx_elems = (size_t)R_TOTAL * T_STEPS;
    const size_t need = gx_elems * 4 + 2 * D_CELL * 8;
    if (ws_size < need) return;
    float* Gx    = (float*)d_ws;
    u64*   slots = (u64*)(Gx + gx_elems);

    lstm_init_kernel<<<16, 256, 0, stream>>>(slots);

    lstm_gx_kernel<<<2048, 256, 0, stream>>>(Wf, bf, Wi, bi, Wc, bc, Wo, bo,
                                             x, Gx);

    lstm_rec_kernel<<<NBLK, NTHR, 0, stream>>>(Wf, Wi, Wc, Wo, Gx, slots, out);
}

// Round 5
// 12969.861 us; speedup vs baseline: 2.3875x; 2.3875x over previous
//
#include <hip/hip_runtime.h>
#include <math.h>

#define D_IN    1024
#define D_CELL  2048
#define T_STEPS 2048
#define D_Z     3072            // D_IN + D_CELL
#define R_TOTAL (4 * D_CELL)    // 8192 gate rows
#define NBLK    256
#define NTHR    1024

// Slot layout: one 128-byte line per CELL-PAIR (the 2 slots one thread polls).
// line l (l = pair = cell>>1) holds cells {2l, 2l+1} at u64 positions 0,1;
// remaining 14 u64 of the line are padding. Two parities (double buffer).
// Round-4 lesson: the all-to-all poll is contention-limited — packing 8-16
// slots per line put ~1000-2000 concurrent pollers on each line. This layout
// cuts it to 256 (one thread per block) and keeps both of a thread's slots
// in ONE private line. Do NOT increase the polling-block count (512-block
// variant regressed 5x: FETCH 300MB -> 1.45GB of poll re-fetch).
#define SLOT_LINE_U64 16        // 128 B
#define SLOT_PAIRS    (D_CELL / 2)              // 1024 lines per parity
#define SLOT_TOTAL    (2 * SLOT_PAIRS * SLOT_LINE_U64)   // u64 count

typedef unsigned long long u64;

// ---------------------------------------------------------------------------
// init: zero the h-exchange slot lines (harness does NOT re-poison ws between
// timed replays; stale tags from a previous replay would satisfy polls).
// slot = (tag<<32)|f32bits(h)
// ---------------------------------------------------------------------------
__global__ void lstm_init_kernel(u64* __restrict__ slots) {
    int i = blockIdx.x * 256 + threadIdx.x;
    if (i < SLOT_TOTAL) slots[i] = 0ull;
}

// ---------------------------------------------------------------------------
// Gx[r][t] = b[r] + sum_k W_g[d][k] * x[k][t]   (k < 1024, input part)
// 1D grid of 2048 blocks, XCD-aware decode: each XCD works on ONE t-half
// (same 4 MiB x tile -> fits its private 4 MiB L2). 256 threads, each
// handles 4 t-columns x 8 rows. W row loads are wave-uniform -> s_load.
// ---------------------------------------------------------------------------
__global__ __launch_bounds__(256) void lstm_gx_kernel(
    const float* __restrict__ Wf, const float* __restrict__ bf,
    const float* __restrict__ Wi, const float* __restrict__ bi,
    const float* __restrict__ Wc, const float* __restrict__ bc,
    const float* __restrict__ Wo, const float* __restrict__ bo,
    const float* __restrict__ x,  float* __restrict__ Gx)
{
    const int bid = blockIdx.x;          // 0..2047
    const int xcd = bid & 7;             // HW round-robin: bid%8 = XCD
    const int loc = bid >> 3;            // 0..255
    const int tx  = xcd >> 2;            // t-half 0/1 (4 XCDs per half)
    const int yb  = (xcd & 3) * 256 + loc;   // row-block 0..1023
    const int tid = threadIdx.x;
    const int t0  = tx * 1024 + tid * 4;
    const int r0  = yb * 8;
    const int g   = r0 >> 11;
    const int d0  = r0 & 2047;
    const float* W = (g == 0) ? Wf : (g == 1) ? Wi : (g == 2) ? Wc : Wo;
    const float* b = (g == 0) ? bf : (g == 1) ? bi : (g == 2) ? bc : bo;

    const float* wr0 = W + (size_t)(d0 + 0) * D_Z;
    const float* wr1 = W + (size_t)(d0 + 1) * D_Z;
    const float* wr2 = W + (size_t)(d0 + 2) * D_Z;
    const float* wr3 = W + (size_t)(d0 + 3) * D_Z;
    const float* wr4 = W + (size_t)(d0 + 4) * D_Z;
    const float* wr5 = W + (size_t)(d0 + 5) * D_Z;
    const float* wr6 = W + (size_t)(d0 + 6) * D_Z;
    const float* wr7 = W + (size_t)(d0 + 7) * D_Z;

    float4 acc[8];
#pragma unroll
    for (int jr = 0; jr < 8; ++jr) acc[jr] = make_float4(0.f, 0.f, 0.f, 0.f);

    for (int k = 0; k < D_IN; k += 4) {
        float4 xa = *(const float4*)(x + (size_t)(k + 0) * T_STEPS + t0);
        float4 xb = *(const float4*)(x + (size_t)(k + 1) * T_STEPS + t0);
        float4 xc = *(const float4*)(x + (size_t)(k + 2) * T_STEPS + t0);
        float4 xd = *(const float4*)(x + (size_t)(k + 3) * T_STEPS + t0);
        const float* wrs[8] = {wr0, wr1, wr2, wr3, wr4, wr5, wr6, wr7};
#pragma unroll
        for (int jr = 0; jr < 8; ++jr) {
            float4 w = *(const float4*)(wrs[jr] + k);   // wave-uniform
            acc[jr].x += w.x * xa.x + w.y * xb.x + w.z * xc.x + w.w * xd.x;
            acc[jr].y += w.x * xa.y + w.y * xb.y + w.z * xc.y + w.w * xd.y;
            acc[jr].z += w.x * xa.z + w.y * xb.z + w.z * xc.z + w.w * xd.z;
            acc[jr].w += w.x * xa.w + w.y * xb.w + w.z * xc.w + w.w * xd.w;
        }
    }

#pragma unroll
    for (int jr = 0; jr < 8; ++jr) {
        float bb = b[d0 + jr];
        float4 o = acc[jr];
        o.x += bb; o.y += bb; o.z += bb; o.w += bb;
        *(float4*)(Gx + (size_t)(r0 + jr) * T_STEPS + t0) = o;
    }
}

// ---------------------------------------------------------------------------
// Persistent recurrence kernel — round-3 skeleton (16 waves, 2 rows per wave,
// weight loads before the loop; the compiler keeps the 64 floats/lane on-chip
// in AGPRs — do NOT add register-class asm, round-2 showed "+v" forces scratch
// spills). ONLY change vs round 3: the de-contended slot-line layout.
// ---------------------------------------------------------------------------
__global__ __launch_bounds__(NTHR, 4) void lstm_rec_kernel(
    const float* __restrict__ Wf, const float* __restrict__ Wi,
    const float* __restrict__ Wc, const float* __restrict__ Wo,
    const float* __restrict__ Gx, u64* __restrict__ slots,
    float* __restrict__ out)
{
    __shared__ float hs[D_CELL];     // h_{t-1}, fp32
    __shared__ float gdot[32];       // per-row reduced dots

    const int tid  = threadIdx.x;
    const int w    = tid >> 6;       // wave 0..15
    const int lane = tid & 63;
    const int r0   = 2 * w;          // rows r0, r0+1  (row = cell*4 + gate)

    // ---- load my two weight rows (fp32, stay on-chip in VGPRs/AGPRs) ----
    const int g0 = r0 & 3,        g1 = (r0 + 1) & 3;
    const int cl = r0 >> 2;                       // same cell for both rows
    const int d  = blockIdx.x * 8 + cl;           // global cell
    const float* Wb0 = ((g0 == 0) ? Wf : (g0 == 1) ? Wi : (g0 == 2) ? Wc : Wo)
                       + (size_t)d * D_Z + D_IN;
    const float* Wb1 = ((g1 == 0) ? Wf : (g1 == 1) ? Wi : (g1 == 2) ? Wc : Wo)
                       + (size_t)d * D_Z + D_IN;
    float4 wA[8], wB[8];
#pragma unroll
    for (int j = 0; j < 8; ++j) {
        wA[j] = *(const float4*)(Wb0 + j * 256 + lane * 4);
        wB[j] = *(const float4*)(Wb1 + j * 256 + lane * 4);
    }

    // Gx row base for lanes 0,1 (lane L handles row r0+L)
    const int myrow = r0 + (lane & 1);
    const size_t gxbase = (size_t)((myrow & 3) * D_CELL
                                   + blockIdx.x * 8 + (myrow >> 2)) * T_STEPS;

    float c = 0.f;                   // cell state (tid<8 threads own cell tid)
    const float L2E  = 1.442695041f;     // log2(e)
    const float L2E2 = 2.885390082f;     // 2*log2(e)

    for (int t = 0; t < T_STEPS; ++t) {
        // prefetch Gx early (independent of poll)
        float gx_pref = 0.f;
        if (lane < 2) gx_pref = Gx[gxbase + t];

        // ---- acquire h_{t-1}: batched poll of my private slot line ----
        if (t == 0) {
            hs[2 * tid]     = 0.f;
            hs[2 * tid + 1] = 0.f;
        } else {
            // line `tid` of parity (t&1): cells {2tid, 2tid+1}
            const u64* bp = slots
                + ((size_t)(t & 1) * SLOT_PAIRS + tid) * SLOT_LINE_U64;
            const u64 tg = (u64)(unsigned)t << 32;
            u64 a, b;
            for (;;) {
                a = __hip_atomic_load(bp + 0, __ATOMIC_RELAXED,
                                      __HIP_MEMORY_SCOPE_AGENT);
                b = __hip_atomic_load(bp + 1, __ATOMIC_RELAXED,
                                      __HIP_MEMORY_SCOPE_AGENT);
                if ((((a ^ tg) | (b ^ tg)) >> 32) == 0) break;
                __builtin_amdgcn_s_sleep(1);
            }
            hs[2 * tid]     = __uint_as_float((unsigned)a);
            hs[2 * tid + 1] = __uint_as_float((unsigned)b);
        }
        __syncthreads();                          // sync A: hs ready

        // ---- two gate-row dot slices from on-chip weights ----
        float acc0 = 0.f, acc1 = 0.f;
#pragma unroll
        for (int j = 0; j < 8; ++j) {
            float4 h = *(const float4*)(hs + j * 256 + lane * 4);
            acc0 += wA[j].x * h.x + wA[j].y * h.y + wA[j].z * h.z + wA[j].w * h.w;
            acc1 += wB[j].x * h.x + wB[j].y * h.y + wB[j].z * h.z + wB[j].w * h.w;
        }
        // paired butterfly: even lanes -> row r0 sum, odd lanes -> row r0+1
        float vK = (lane & 1) ? acc1 : acc0;
        float vO = (lane & 1) ? acc0 : acc1;
        float v  = vK + __shfl_xor(vO, 1);
        v += __shfl_xor(v, 2);
        v += __shfl_xor(v, 4);
        v += __shfl_xor(v, 8);
        v += __shfl_xor(v, 16);
        v += __shfl_xor(v, 32);
        if (lane < 2) gdot[r0 + lane] = v + gx_pref;
        __syncthreads();                          // sync B: gdot ready

        // ---- activations: one thread per owned cell (fast exp2/rcp) ----
        if (tid < 8) {
            float gf = gdot[tid * 4 + 0], gi = gdot[tid * 4 + 1];
            float gc = gdot[tid * 4 + 2], go = gdot[tid * 4 + 3];
            float f    = __builtin_amdgcn_rcpf(
                             1.f + __builtin_amdgcn_exp2f(-L2E * gf));
            float ig   = __builtin_amdgcn_rcpf(
                             1.f + __builtin_amdgcn_exp2f(-L2E * gi));
            float o    = __builtin_amdgcn_rcpf(
                             1.f + __builtin_amdgcn_exp2f(-L2E * go));
            float cand = 1.f - 2.f * __builtin_amdgcn_rcpf(
                             __builtin_amdgcn_exp2f(L2E2 * gc) + 1.f);
            c = f * c + ig * cand;
            float tc   = 1.f - 2.f * __builtin_amdgcn_rcpf(
                             __builtin_amdgcn_exp2f(L2E2 * c) + 1.f);
            float hn = o * tc;
            const int dg = blockIdx.x * 8 + tid;  // my global cell
            if (t + 1 < T_STEPS) {                // publish FIRST
                u64 pk = ((u64)(unsigned)(t + 1) << 32)
                       | (u64)__float_as_uint(hn);
                __hip_atomic_store(
                    slots + ((size_t)((t + 1) & 1) * SLOT_PAIRS + (dg >> 1))
                              * SLOT_LINE_U64 + (dg & 1),
                    pk, __ATOMIC_RELAXED, __HIP_MEMORY_SCOPE_AGENT);
            }
            out[(size_t)dg * T_STEPS + t] = hn;
        }
        // no third sync needed: hs writes for t+1 happen after this block's
        // compute reads (pre sync B); gdot/c for t+1 written after sync A(t+1)
    }
}

// ---------------------------------------------------------------------------
extern "C" void kernel_launch(void* const* d_in, const int* in_sizes, int n_in,
                              void* d_out, int out_size, void* d_ws, size_t ws_size,
                              hipStream_t stream) {
    const float* x  = (const float*)d_in[0];
    const float* Wf = (const float*)d_in[1];
    const float* bf = (const float*)d_in[2];
    const float* Wi = (const float*)d_in[3];
    const float* bi = (const float*)d_in[4];
    const float* Wc = (const float*)d_in[5];
    const float* bc = (const float*)d_in[6];
    const float* Wo = (const float*)d_in[7];
    const float* bo = (const float*)d_in[8];
    float* out = (float*)d_out;

    // ws layout: Gx fp32 [8192][2048] | slot lines u64[2][1024][16]
    const size_t gx_elems = (size_t)R_TOTAL * T_STEPS;
    const size_t need = gx_elems * 4 + (size_t)SLOT_TOTAL * 8;
    if (ws_size < need) return;
    float* Gx    = (float*)d_ws;
    u64*   slots = (u64*)(Gx + gx_elems);

    lstm_init_kernel<<<(SLOT_TOTAL + 255) / 256, 256, 0, stream>>>(slots);

    lstm_gx_kernel<<<2048, 256, 0, stream>>>(Wf, bf, Wi, bi, Wc, bc, Wo, bo,
                                             x, Gx);

    lstm_rec_kernel<<<NBLK, NTHR, 0, stream>>>(Wf, Wi, Wc, Wo, Gx, slots, out);
}